// Round 8
// baseline (94849.335 us; speedup 1.0000x reference)
//
#include <hip/hip_runtime.h>
#include <math.h>

// Problem dims (fixed by the reference)
#define T_DIM   512
#define B_DIM   64
#define INP_DIM 512
#define HS_DIM  2048
#define OUT_DIM 512
#define SLOT    (HS_DIM * B_DIM)   // 131072 floats = 512 KB per state slot

// ws ring layout: h ring (T+1 slots) then r ring (T slots)
#define WS_NEED ((size_t)(2 * T_DIM + 1) * SLOT * sizeof(float))  // ~512.5 MB

// Device-global scratch. NOTE (round-7 finding): __device__ globals appear to
// be L2-uncached (fine-grained) on this part — fine for single-use streams
// (dataT, prex), fatal for the multiply-re-read state rings (moved to d_ws).
static __device__ float g_dataT[(size_t)T_DIM * INP_DIM * B_DIM]; // [t][k][b]
static __device__ float g_prex[(size_t)T_DIM * HS_DIM * B_DIM];   // [t][j][b]
// Fallback rings (used only if ws_size < WS_NEED)
static __device__ float g_hring_fb[(size_t)(T_DIM + 1) * SLOT];
static __device__ float g_rring_fb[(size_t)T_DIM * SLOT];
// 2-level global barrier (monotonic counters, reset each call)
static __device__ unsigned g_sub[8 * 16];                         // 8 counters, 64B-spaced
static __device__ unsigned g_rel;

__global__ __launch_bounds__(256) void zero_state_kernel(float* __restrict__ hring) {
    int i = blockIdx.x * 256 + threadIdx.x;
    if (i < SLOT) hring[i] = 0.f;
    if (i < 8) g_sub[i * 16] = 0u;
    if (i == 8) g_rel = 0u;
}

// data [t][b][k] -> g_dataT [t][k][b]
__global__ __launch_bounds__(256) void transpose_data_kernel(const float* __restrict__ data) {
    __shared__ float tile[64][65];
    const int t = blockIdx.x;
    const float* src = data + (size_t)t * B_DIM * INP_DIM;
    float* dst = g_dataT + (size_t)t * INP_DIM * B_DIM;
    for (int kt = 0; kt < INP_DIM / 64; ++kt) {
        const int k0 = kt * 64;
        __syncthreads();
        for (int i = threadIdx.x; i < 64 * 64; i += 256) {
            int b = i >> 6, kk = i & 63;
            tile[b][kk] = src[b * INP_DIM + k0 + kk];
        }
        __syncthreads();
        for (int i = threadIdx.x; i < 64 * 64; i += 256) {
            int k = i >> 6, b2 = i & 63;
            dst[(size_t)(k0 + k) * B_DIM + b2] = tile[b2][k];
        }
    }
}

// g_prex[t][j][b] = bih[j] + bhh[j] + sum_k dataT[t][k][b] * Wih[j][k]
__global__ __launch_bounds__(256) void prex_kernel(const float* __restrict__ Wih,
                                                   const float* __restrict__ bih,
                                                   const float* __restrict__ bhh) {
    __shared__ float lds[128 * B_DIM];
    const int t = blockIdx.y;
    const int lane = threadIdx.x & 63;
    const int wv = __builtin_amdgcn_readfirstlane(threadIdx.x >> 6);
    const int j0 = blockIdx.x * 32 + wv * 8;
    const float* xT = g_dataT + (size_t)t * INP_DIM * B_DIM;
    float acc[8] = {};
    for (int k0 = 0; k0 < INP_DIM; k0 += 128) {
        __syncthreads();
        {
            const float4* s4 = (const float4*)(xT + (size_t)k0 * B_DIM);
            float4* d4 = (float4*)lds;
            for (int i = threadIdx.x; i < 128 * B_DIM / 4; i += 256) d4[i] = s4[i];
        }
        __syncthreads();
        for (int k = 0; k < 128; k += 4) {
            float w[8][4];
            #pragma unroll
            for (int c = 0; c < 8; ++c)
                #pragma unroll
                for (int u = 0; u < 4; ++u)
                    w[c][u] = Wih[(size_t)(j0 + c) * INP_DIM + k0 + k + u];
            #pragma unroll
            for (int u = 0; u < 4; ++u) {
                float hv = lds[(k + u) * B_DIM + lane];
                #pragma unroll
                for (int c = 0; c < 8; ++c) acc[c] += hv * w[c][u];
            }
        }
    }
    #pragma unroll
    for (int c = 0; c < 8; ++c) {
        int j = j0 + c;
        g_prex[((size_t)t * HS_DIM + j) * B_DIM + lane] = acc[c] + bih[j] + bhh[j];
    }
}

// Wave computes one K-eighth (64 k4) of the block's 8 output columns.
// State read with plain cached float4 loads from the (cacheable) ws ring slot;
// weights from LDS. Register double-buffered, static indexing only.
__device__ __forceinline__ void eighth_gemm(float acc[8], const float* __restrict__ srcT4,
                                            const float* __restrict__ wl,
                                            int kq4, int lane) {
    const float4* gp = (const float4*)srcT4 + (size_t)kq4 * 64 + lane;
    float4 bufA[8], bufB[8];
    #pragma unroll
    for (int r = 0; r < 8; ++r) bufA[r] = gp[r * 64];
    #pragma unroll 1
    for (int ch = 0; ch < 8; ch += 2) {
        #pragma unroll
        for (int r = 0; r < 8; ++r) bufB[r] = gp[((ch + 1) * 8 + r) * 64];
        #pragma unroll
        for (int r = 0; r < 8; ++r) {
            const float4 h4 = bufA[r];
            const int k = (kq4 + ch * 8 + r) * 4;
            #pragma unroll
            for (int c = 0; c < 8; ++c) {
                const float4 w = *(const float4*)&wl[c * HS_DIM + k];
                acc[c] = fmaf(h4.x, w.x, acc[c]);
                acc[c] = fmaf(h4.y, w.y, acc[c]);
                acc[c] = fmaf(h4.z, w.z, acc[c]);
                acc[c] = fmaf(h4.w, w.w, acc[c]);
            }
        }
        if (ch + 2 < 8) {
            #pragma unroll
            for (int r = 0; r < 8; ++r) bufA[r] = gp[((ch + 2) * 8 + r) * 64];
        }
        #pragma unroll
        for (int r = 0; r < 8; ++r) {
            const float4 h4 = bufB[r];
            const int k = (kq4 + (ch + 1) * 8 + r) * 4;
            #pragma unroll
            for (int c = 0; c < 8; ++c) {
                const float4 w = *(const float4*)&wl[c * HS_DIM + k];
                acc[c] = fmaf(h4.x, w.x, acc[c]);
                acc[c] = fmaf(h4.y, w.y, acc[c]);
                acc[c] = fmaf(h4.z, w.z, acc[c]);
                acc[c] = fmaf(h4.w, w.w, acc[c]);
            }
        }
    }
}

// 2-level global barrier, no cache maintenance: sc1 stores are at the coherence
// point once vmcnt==0; arrival = 1 sub-counter add (32/counter), last arriver
// of each group bumps central release; leaders poll central.
__device__ __forceinline__ void gbar(unsigned nbar) {
    asm volatile("s_waitcnt vmcnt(0)" ::: "memory"); // publish my sc1 stores
    __syncthreads();
    if (threadIdx.x == 0) {
        unsigned v = __hip_atomic_fetch_add(&g_sub[(blockIdx.x & 7) * 16], 1u,
                                            __ATOMIC_RELAXED, __HIP_MEMORY_SCOPE_AGENT) + 1;
        if (v == nbar * 32u)
            __hip_atomic_fetch_add(&g_rel, 1u, __ATOMIC_RELAXED, __HIP_MEMORY_SCOPE_AGENT);
        while (__hip_atomic_load(&g_rel, __ATOMIC_RELAXED, __HIP_MEMORY_SCOPE_AGENT) < nbar * 8u)
            __builtin_amdgcn_s_sleep(2);
    }
    __syncthreads();
}

// Persistent kernel: all 512 recurrent steps. 256 blocks (1/CU) x 512 threads.
// Block owns 8 output cols; weight slices (64 KB each) in static LDS.
// Wave wv: epilogue col j0+wv AND k-slice (wv+blockIdx)&7 (stagger decorrelates
// same-line misses across blocks). pot in registers. State: cacheable ws ring,
// published with sc1 stores, consumed with plain cached loads.
__global__ __launch_bounds__(512, 1) void rnn_persistent(const float* __restrict__ Whh,
                                                         const float* __restrict__ Wp,
                                                         const float* __restrict__ bp,
                                                         const float* __restrict__ decay,
                                                         float* __restrict__ hring,
                                                         float* __restrict__ rring) {
    __shared__ float w_hh[8 * HS_DIM];   // 64 KB
    __shared__ float w_p[8 * HS_DIM];    // 64 KB
    __shared__ float red[8 * 8 * 64];    // 16 KB [wave][col][b]
    __shared__ float stage[8 * 64];      // 2 KB  [col][b]

    const int j0 = blockIdx.x * 8;
    const int lane = threadIdx.x & 63;
    const int wv = threadIdx.x >> 6;                    // 0..7
    const int kq4 = ((wv + blockIdx.x) & 7) * 64;       // staggered k-slice

    // one-time weight preload into LDS (cacheable loads)
    {
        const float4* A = (const float4*)(Whh + (size_t)j0 * HS_DIM);
        const float4* B = (const float4*)(Wp + (size_t)j0 * HS_DIM);
        float4* a = (float4*)w_hh;
        float4* b = (float4*)w_p;
        for (int i = threadIdx.x; i < 8 * HS_DIM / 4; i += 512) { a[i] = A[i]; b[i] = B[i]; }
    }
    const int jj = j0 + wv;
    const float bpv = bp[jj];
    const float dev = decay[jj];
    float pot = 0.f;
    unsigned nbar = 0;
    __syncthreads();

    for (int t = 0; t < T_DIM; ++t) {
        // ---------- Phase A: r = tanh(prex[t] + h @ Whh^T) ----------
        {
            const float* hbuf = hring + (size_t)t * SLOT;
            float acc[8] = {};
            eighth_gemm(acc, hbuf, w_hh, kq4, lane);
            #pragma unroll
            for (int c = 0; c < 8; ++c) red[(wv * 8 + c) * 64 + lane] = acc[c];
            __syncthreads();
            float s = 0.f;
            #pragma unroll
            for (int w = 0; w < 8; ++w) s += red[(w * 8 + wv) * 64 + lane];
            stage[wv * 64 + lane] =
                tanhf(g_prex[((size_t)t * HS_DIM + jj) * B_DIM + lane] + s);
            __syncthreads();
            if (threadIdx.x < 128) { // waves 0-1: coalesced sc1 publish
                const int q = wv;
                float2 lo = make_float2(stage[(q * 4 + 0) * 64 + lane],
                                        stage[(q * 4 + 1) * 64 + lane]);
                float2 hi = make_float2(stage[(q * 4 + 2) * 64 + lane],
                                        stage[(q * 4 + 3) * 64 + lane]);
                unsigned long long* dst =
                    (unsigned long long*)(rring + (size_t)t * SLOT +
                                          ((size_t)(j0 >> 2) + q) * 256) + lane * 2;
                __hip_atomic_store(dst, __builtin_bit_cast(unsigned long long, lo),
                                   __ATOMIC_RELAXED, __HIP_MEMORY_SCOPE_AGENT);
                __hip_atomic_store(dst + 1, __builtin_bit_cast(unsigned long long, hi),
                                   __ATOMIC_RELAXED, __HIP_MEMORY_SCOPE_AGENT);
            }
        }
        gbar(++nbar);
        // ---------- Phase B: p = pot + r @ Wp^T + bp; h = relu(p); pot = min(p,0)*decay ----------
        {
            const float* rbuf = rring + (size_t)t * SLOT;
            float acc[8] = {};
            eighth_gemm(acc, rbuf, w_p, kq4, lane);
            #pragma unroll
            for (int c = 0; c < 8; ++c) red[(wv * 8 + c) * 64 + lane] = acc[c];
            __syncthreads();
            float s = 0.f;
            #pragma unroll
            for (int w = 0; w < 8; ++w) s += red[(w * 8 + wv) * 64 + lane];
            float p = pot + s + bpv;
            stage[wv * 64 + lane] = fmaxf(p, 0.f);
            pot = fminf(p, 0.f) * dev;
            __syncthreads();
            if (threadIdx.x < 128) {
                const int q = wv;
                float2 lo = make_float2(stage[(q * 4 + 0) * 64 + lane],
                                        stage[(q * 4 + 1) * 64 + lane]);
                float2 hi = make_float2(stage[(q * 4 + 2) * 64 + lane],
                                        stage[(q * 4 + 3) * 64 + lane]);
                unsigned long long* dst =
                    (unsigned long long*)(hring + (size_t)(t + 1) * SLOT +
                                          ((size_t)(j0 >> 2) + q) * 256) + lane * 2;
                __hip_atomic_store(dst, __builtin_bit_cast(unsigned long long, lo),
                                   __ATOMIC_RELAXED, __HIP_MEMORY_SCOPE_AGENT);
                __hip_atomic_store(dst + 1, __builtin_bit_cast(unsigned long long, hi),
                                   __ATOMIC_RELAXED, __HIP_MEMORY_SCOPE_AGENT);
            }
        }
        gbar(++nbar);
    }
}

// out[b][o] = bout[o] + sum_j h[j][b] * Wout[o][j]  (reads final ring slot)
__global__ __launch_bounds__(256) void out_kernel(const float* __restrict__ Wout,
                                                  const float* __restrict__ bout,
                                                  float* __restrict__ out,
                                                  const float* __restrict__ hring) {
    const float* hT4 = hring + (size_t)T_DIM * SLOT;
    const int lane = threadIdx.x & 63;
    const int wv = __builtin_amdgcn_readfirstlane(threadIdx.x >> 6);
    const int o0 = blockIdx.x * 16 + wv * 4;
    float acc[4] = {};
    for (int k4 = 0; k4 < HS_DIM / 4; ++k4) {
        float4 h4 = *(const float4*)&hT4[(size_t)k4 * 256 + lane * 4];
        #pragma unroll
        for (int c = 0; c < 4; ++c) {
            const float* w = Wout + (size_t)(o0 + c) * HS_DIM + (size_t)k4 * 4;
            acc[c] = fmaf(h4.x, w[0], acc[c]);
            acc[c] = fmaf(h4.y, w[1], acc[c]);
            acc[c] = fmaf(h4.z, w[2], acc[c]);
            acc[c] = fmaf(h4.w, w[3], acc[c]);
        }
    }
    #pragma unroll
    for (int c = 0; c < 4; ++c)
        out[(size_t)lane * OUT_DIM + o0 + c] = acc[c] + bout[o0 + c];
}

extern "C" void kernel_launch(void* const* d_in, const int* in_sizes, int n_in,
                              void* d_out, int out_size, void* d_ws, size_t ws_size,
                              hipStream_t stream) {
    const float* data  = (const float*)d_in[0];
    const float* Wih   = (const float*)d_in[1];
    const float* bih   = (const float*)d_in[2];
    const float* Whh   = (const float*)d_in[3];
    const float* bhh   = (const float*)d_in[4];
    const float* Wp    = (const float*)d_in[5];
    const float* bp    = (const float*)d_in[6];
    const float* decay = (const float*)d_in[7];
    const float* Wout  = (const float*)d_in[8];
    const float* bout  = (const float*)d_in[9];
    float* out = (float*)d_out;

    // Rings in the (L2-cacheable) harness workspace if it's big enough;
    // otherwise fall back to device-global rings (round-7 behavior).
    float* hring;
    float* rring;
    if (ws_size >= WS_NEED) {
        hring = (float*)d_ws;
        rring = hring + (size_t)(T_DIM + 1) * SLOT;
    } else {
        hipGetSymbolAddress((void**)&hring, HIP_SYMBOL(g_hring_fb));
        hipGetSymbolAddress((void**)&rring, HIP_SYMBOL(g_rring_fb));
    }

    zero_state_kernel<<<(SLOT + 255) / 256, 256, 0, stream>>>(hring);
    transpose_data_kernel<<<T_DIM, 256, 0, stream>>>(data);
    prex_kernel<<<dim3(HS_DIM / 32, T_DIM), 256, 0, stream>>>(Wih, bih, bhh);
    rnn_persistent<<<dim3(256), dim3(512), 0, stream>>>(Whh, Wp, bp, decay, hring, rring);
    out_kernel<<<OUT_DIM / 16, 256, 0, stream>>>(Wout, bout, out, hring);
}